// Round 17
// baseline (73.225 us; speedup 1.0000x reference)
//
#include <hip/hip_runtime.h>

typedef float v4f   __attribute__((ext_vector_type(4)));
typedef float f32x4 __attribute__((ext_vector_type(4)));
typedef _Float16 h4 __attribute__((ext_vector_type(4)));
typedef _Float16 h8 __attribute__((ext_vector_type(8)));

#define HH 512
#define WW 512
#define NPLANES 96
#define NSTRIP 32
#define NUNIT (NPLANES * NSTRIP)   // 3072 waves, one per (plane,strip)
#define C1V 1e-4f
#define C2V 9e-4f
#define EPSV 1e-8f
#define NPIX 25165824.0f           // 32*3*512*512

// raw ring at lds+0: 3 slots x [array 2][row 16][40 f32] = 3 x 5120 B
#define RAW_SLOT 5120
#define RAW_ARR  2560
#define RAW_ROW  160
// H ring at lds+15360: [q 5][slot 4][col 16][48 B] + 16B/slot pad (SLOT_B=784)
#define HR_BASE  15360
#define SLOT_B   784
#define Q_B      3136
#define LDS_B    31040

#define MF(A, B) __builtin_amdgcn_mfma_f32_16x16x32_f16((A), (B), zf, 0, 0, 0)

__device__ __forceinline__ void gld16(const float* g, char* l) {
  __builtin_amdgcn_global_load_lds((const __attribute__((address_space(1))) void*)g,
                                   (__attribute__((address_space(3))) void*)l, 16, 0, 0);
}

// 11-way select from named weight scalars (no arrays -> no scratch)
#define SELW(DST, IX) { const int ix_ = (IX); float r_ = 0.f; \
  r_ = (ix_ == 0) ? wv0 : r_;  r_ = (ix_ == 1) ? wv1 : r_; \
  r_ = (ix_ == 2) ? wv2 : r_;  r_ = (ix_ == 3) ? wv3 : r_; \
  r_ = (ix_ == 4) ? wv4 : r_;  r_ = (ix_ == 5) ? wv5 : r_; \
  r_ = (ix_ == 6) ? wv6 : r_;  r_ = (ix_ == 7) ? wv7 : r_; \
  r_ = (ix_ == 8) ? wv8 : r_;  r_ = (ix_ == 9) ? wv9 : r_; \
  r_ = (ix_ == 10) ? wv10 : r_; DST = r_; }

#define PACK8(DST, F0,F1,F2,F3,F4,F5,F6,F7) \
  DST = (h8){(_Float16)(F0),(_Float16)(F1),(_Float16)(F2),(_Float16)(F3), \
             (_Float16)(F4),(_Float16)(F5),(_Float16)(F6),(_Float16)(F7)};

#define EPX(M) { \
  const float mux_ = mx[M], muy_ = my[M]; \
  const float mx2_ = mux_ * mux_, my2_ = muy_ * muy_, mxy_ = mux_ * muy_; \
  const float sx2_ = vx2[M] - mx2_, sy2_ = vy2[M] - my2_, sxy_ = vxy[M] - mxy_; \
  const float num_ = fmaf(2.f, mxy_, C1V) * fmaf(2.f, sxy_, C2V); \
  const float den_ = (mx2_ + my2_ + C1V) * (sx2_ + sy2_ + C2V) + EPSV; \
  acc##M = fmaf(num_, __builtin_amdgcn_rcpf(den_), acc##M); }

// V operand fetch for out-chunk O: lane (n,s) reads 8 rows of col n from
// H chunk c = O-1+{0,1,1,2}; chunks -1 (slot 3) and 32 (slot 0) hold genuine
// zeros (weight-killed H steps).
#define VLOADL(O) { \
  const int c_ = (O) - 1 + ((s + 1) >> 1); \
  const char* rb_ = hlds + (c_ & 3) * SLOT_B + rByte; \
  vbx  = *(const h8*)(rb_); \
  vby  = *(const h8*)(rb_ + Q_B); \
  vbx2 = *(const h8*)(rb_ + 2 * Q_B); \
  vby2 = *(const h8*)(rb_ + 3 * Q_B); \
  vbxy = *(const h8*)(rb_ + 4 * Q_B); }

#define VMFMA { \
  const f32x4 mx  = MF(Wf, vbx);  const f32x4 my  = MF(Wf, vby); \
  const f32x4 vx2 = MF(Wf, vbx2); const f32x4 vy2 = MF(Wf, vby2); \
  const f32x4 vxy = MF(Wf, vbxy); \
  EPX(0) EPX(1) EPX(2) EPX(3) }

__global__ __launch_bounds__(64)
void ssim_main(const float* __restrict__ x, const float* __restrict__ y,
               float* __restrict__ partial)
{
  __shared__ __attribute__((aligned(16))) char lds[LDS_B];

  const int l = threadIdx.x;
  const int n = l & 15;     // H: image row in chunk; V: out col
  const int s = l >> 4;     // k quadrant

  // XCD swizzle: 384 consecutive (plane,strip) units per XCD
  const int wg = blockIdx.x;
  const int swz = (wg & 7) * (NUNIT / 8) + (wg >> 3);
  const int plane = swz >> 5;
  const int strip = swz & 31;
  const int C0 = strip * 16;

  const float* xp = x + (size_t)plane * (HH * WW);
  const float* yp = y + (size_t)plane * (HH * WW);

  // Gaussian window (exact reference formula), named scalars -> SGPRs
  float wv0, wv1, wv2, wv3, wv4, wv5, wv6, wv7, wv8, wv9, wv10;
#define WINIT(k) wv##k = expf(-((float)((k - 5) * (k - 5))) / 4.5f);
  WINIT(0) WINIT(1) WINIT(2) WINIT(3) WINIT(4) WINIT(5)
  WINIT(6) WINIT(7) WINIT(8) WINIT(9) WINIT(10)
#undef WINIT
  const float inv_ = 1.f / (wv0 + wv1 + wv2 + wv3 + wv4 + wv5 + wv6 + wv7 + wv8 + wv9 + wv10);
#define WNORM(k) wv##k = __int_as_float(__builtin_amdgcn_readfirstlane(__float_as_int(wv##k * inv_)));
  WNORM(0) WNORM(1) WNORM(2) WNORM(3) WNORM(4) WNORM(5)
  WNORM(6) WNORM(7) WNORM(8) WNORM(9) WNORM(10)
#undef WNORM

  const f32x4 zf = {0.f, 0.f, 0.f, 0.f};

  // shared banded weight fragment W[k][i] = w[k-i-3] (B in H, A in V)
  h8 Wf;
  {
    const int kb = 8 * s;
    float b0,b1,b2,b3,b4,b5,b6,b7;
    SELW(b0, kb + 0 - n - 3) SELW(b1, kb + 1 - n - 3)
    SELW(b2, kb + 2 - n - 3) SELW(b3, kb + 3 - n - 3)
    SELW(b4, kb + 4 - n - 3) SELW(b5, kb + 5 - n - 3)
    SELW(b6, kb + 6 - n - 3) SELW(b7, kb + 7 - n - 3)
    PACK8(Wf, b0,b1,b2,b3,b4,b5,b6,b7)
  }

  // H col window: cols C0-8+8s..+7; fully-outside groups killed via zero weights
  // (strip 0/s=0, strip 31/s=3). Raw staging clamps cols -> garbage only lands
  // in killed groups.
  const int cb = C0 - 8 + 8 * s;
  const bool kill = (cb < 0) || (cb >= WW);
  h8 WfH = Wf;
  if (kill) WfH = (h8)(_Float16)0.f;

  // per-lane DMA source base (chunk 0): instr q writes raw-slot bytes
  // [q*1024 + 16*lane); layout [array 2][row 16][40 f32]; cols clamped.
  const float *pQ0, *pQ1, *pQ2, *pQ3, *pQ4;
#define MKQ(Q, P) { \
  const int o_ = (Q) * 1024 + 16 * l; \
  const int a_ = o_ / RAW_ARR; \
  const int rem_ = o_ % RAW_ARR; \
  const int r_ = rem_ / RAW_ROW; \
  const int cf_ = (rem_ % RAW_ROW) >> 2; \
  const int ca_ = min(max(C0 - 8 + cf_, 0), WW - 4); \
  P = (a_ ? yp : xp) + r_ * WW + ca_; }
  MKQ(0, pQ0) MKQ(1, pQ1) MKQ(2, pQ2) MKQ(3, pQ3) MKQ(4, pQ4)
#undef MKQ

  const int wByte = n * 48 + 8 * s;              // H store: col n, rows 4s..4s+3
  const int rByte = n * 48 + 16 * ((s + 1) & 1); // V read: col n, rowbase {8,0,8,0}
  const int rawOff = n * RAW_ROW + 32 * s;       // raw A-frag: row n, floats 8s..
  char* hlds = lds + HR_BASE;

  h8 vbx, vby, vbx2, vby2, vbxy;
  float acc0 = 0.f, acc1 = 0.f, acc2 = 0.f, acc3 = 0.f;

  // prologue: DMA chunks 0,1,2 into slots 0,1,2 (15 instrs)
  #pragma unroll
  for (int k = 0; k < 3; ++k) {
    char* db = lds + k * RAW_SLOT;
    const int off = k * 8192;     // 16 rows * 512 cols (floats)
    gld16(pQ0 + off, db);        gld16(pQ1 + off, db + 1024);
    gld16(pQ2 + off, db + 2048); gld16(pQ3 + off, db + 3072);
    gld16(pQ4 + off, db + 4096);
  }

  // 34 steps: H chunk t = tt-1 (t<0 / t>31 weight-killed); V out-chunk tt-3.
  #pragma unroll 1
  for (int tt = 0; tt < 34; ++tt) {
    if (tt >= 3) { VLOADL(tt - 3) }

    // DMA chunk d = min(tt+1,31) into slot d%3 (dups at edges are benign:
    // same data rewritten). 5 instrs/step -> uniform counted vmcnt.
    { const int d = min(tt + 1, 31);
      char* db = lds + (d % 3) * RAW_SLOT;
      const int off = d * 8192;
      gld16(pQ0 + off, db);        gld16(pQ1 + off, db + 1024);
      gld16(pQ2 + off, db + 2048); gld16(pQ3 + off, db + 3072);
      gld16(pQ4 + off, db + 4096); }
    // chunks tt, tt+1 (10 instrs) stay in flight; chunk tt-1 has landed
    asm volatile("s_waitcnt vmcnt(10)" ::: "memory");

    // raw A-frags from LDS (chunk c = clamp(tt-1,0,31))
    const int c = min(max(tt - 1, 0), 31);
    const char* rb = lds + (c % 3) * RAW_SLOT + rawOff;
    const v4f xr0 = *(const v4f*)(rb);
    const v4f xr1 = *(const v4f*)(rb + 16);
    const v4f yr0 = *(const v4f*)(rb + RAW_ARR);
    const v4f yr1 = *(const v4f*)(rb + RAW_ARR + 16);

    h8 ax, ay;
    PACK8(ax, xr0[0],xr0[1],xr0[2],xr0[3], xr1[0],xr1[1],xr1[2],xr1[3])
    PACK8(ay, yr0[0],yr0[1],yr0[2],yr0[3], yr1[0],yr1[1],yr1[2],yr1[3])
    const bool rOK = (unsigned)(tt - 1) < 32u;
    const h8 wfh = rOK ? WfH : (h8)(_Float16)0.f;
    const h8 ax2 = ax * ax, ay2 = ay * ay, axy = ax * ay;
    const f32x4 chx  = MF(ax,  wfh); const f32x4 chy  = MF(ay,  wfh);
    const f32x4 chx2 = MF(ax2, wfh); const f32x4 chy2 = MF(ay2, wfh);
    const f32x4 chxy = MF(axy, wfh);
    { char* wb = hlds + ((tt - 1) & 3) * SLOT_B + wByte;
      *(h4*)(wb)         = (h4){(_Float16)chx[0], (_Float16)chx[1], (_Float16)chx[2], (_Float16)chx[3]};
      *(h4*)(wb + Q_B)   = (h4){(_Float16)chy[0], (_Float16)chy[1], (_Float16)chy[2], (_Float16)chy[3]};
      *(h4*)(wb + 2*Q_B) = (h4){(_Float16)chx2[0],(_Float16)chx2[1],(_Float16)chx2[2],(_Float16)chx2[3]};
      *(h4*)(wb + 3*Q_B) = (h4){(_Float16)chy2[0],(_Float16)chy2[1],(_Float16)chy2[2],(_Float16)chy2[3]};
      *(h4*)(wb + 4*Q_B) = (h4){(_Float16)chxy[0],(_Float16)chxy[1],(_Float16)chxy[2],(_Float16)chxy[3]}; }

    if (tt >= 3) { VMFMA }
  }
  // tail: last out-chunk
  VLOADL(31) VMFMA

  // drain outstanding DMA before LDS goes away
  asm volatile("s_waitcnt vmcnt(0)" ::: "memory");

  float a = (acc0 + acc1) + (acc2 + acc3);
  #pragma unroll
  for (int off = 32; off > 0; off >>= 1) a += __shfl_down(a, off);
  if (l == 0) partial[swz] = a;
}

__global__ void finalize_kernel(const float* __restrict__ partial, float* __restrict__ out)
{
  __shared__ float s4[4];
  float a = 0.f;
  for (int i = threadIdx.x; i < NUNIT; i += 256) a += partial[i];
  #pragma unroll
  for (int off = 32; off > 0; off >>= 1) a += __shfl_down(a, off);
  if ((threadIdx.x & 63) == 0) s4[threadIdx.x >> 6] = a;
  __syncthreads();
  if (threadIdx.x == 0) out[0] = 1.f - (s4[0] + s4[1] + s4[2] + s4[3]) * (1.f / NPIX);
}

extern "C" void kernel_launch(void* const* d_in, const int* in_sizes, int n_in,
                              void* d_out, int out_size, void* d_ws, size_t ws_size,
                              hipStream_t stream)
{
  const float* x = (const float*)d_in[0];
  const float* y = (const float*)d_in[1];
  float* ws = (float*)d_ws;
  float* out = (float*)d_out;

  hipLaunchKernelGGL(ssim_main, dim3(NUNIT), dim3(64), 0, stream, x, y, ws);
  hipLaunchKernelGGL(finalize_kernel, dim3(1), dim3(256), 0, stream, ws, out);
}